// Round 2
// baseline (4453.680 us; speedup 1.0000x reference)
//
#include <hip/hip_runtime.h>
#include <hip/hip_bf16.h>

#define NN 50000
#define NE 800000
#define DIN 128
#define DH 256
#define NG 64

__device__ __forceinline__ float bf2f(__hip_bfloat16 v) { return __bfloat162float(v); }

// flag-driven generic accessors: fbf=1 -> floats stored as bf16; i64=1 -> ints stored as int64
__device__ __forceinline__ float loadF(const void* p, long i, int fbf) {
  return fbf ? bf2f(((const __hip_bfloat16*)p)[i]) : ((const float*)p)[i];
}
__device__ __forceinline__ void storeF(void* p, long i, float v, int fbf) {
  if (fbf) ((__hip_bfloat16*)p)[i] = __float2bfloat16(v);
  else ((float*)p)[i] = v;
}
__device__ __forceinline__ int loadI(const void* p, long i, int i64) {
  return i64 ? (int)((const long long*)p)[i] : ((const int*)p)[i];
}

// Detect dtypes from raw bit patterns (deterministic in practice, see analysis).
__global__ void k_detect(const void* x, const void* ei, int* flags) {
  __shared__ int s_f32sig, s_i32sig;
  if (threadIdx.x == 0) { s_f32sig = 0; s_i32sig = 0; }
  __syncthreads();
  int t = threadIdx.x;
  // x as uint16: bf16 mode -> all words < 0x3F80 (values in [0,1)).
  // f32 mode -> even words are low mantissa halves, uniform over 16 bits.
  const unsigned short* u = (const unsigned short*)x;
  int f = 0;
  for (int i = 2 * t; i < 8192; i += 512) if (u[i] >= 0x4000) f = 1;
  // ei as uint32: int64 mode -> odd words (high halves) are all 0.
  // int32 mode -> odd words are random node indices, some nonzero.
  const unsigned int* w = (const unsigned int*)ei;
  int g = 0;
  for (int i = 2 * t + 1; i < 8192; i += 512) if (w[i] != 0u) g = 1;
  if (f) atomicOr(&s_f32sig, 1);
  if (g) atomicOr(&s_i32sig, 1);
  __syncthreads();
  if (t == 0) { flags[0] = s_f32sig ? 0 : 1; flags[1] = s_i32sig ? 0 : 1; }
}

__global__ void k_zero(float* __restrict__ p, int n) {
  int i = blockIdx.x * blockDim.x + threadIdx.x;
  int stride = gridDim.x * blockDim.x;
  for (; i < n; i += stride) p[i] = 0.0f;
}

__global__ void k_colsum(const void* __restrict__ x, float* __restrict__ colsum,
                         const int* __restrict__ flags) {
  int fbf = flags[0];
  int col = threadIdx.x;  // 0..127
  float acc = 0.f;
  for (int r = blockIdx.x; r < NN; r += gridDim.x)
    acc += loadF(x, (long)r * DIN + col, fbf);
  atomicAdd(&colsum[col], acc);
}

__global__ void k_handcrafted(const float* __restrict__ colsum, void* __restrict__ out,
                              const int* __restrict__ flags) {
  __shared__ float s[DIN];
  int fbf = flags[0];
  int t = threadIdx.x;
  s[t] = colsum[t];
  __syncthreads();
  for (int off = DIN / 2; off > 0; off >>= 1) {
    if (t < off) s[t] += s[t + off];
    __syncthreads();
  }
  float g = s[0];
  storeF(out, NG * DH + t, colsum[t] / g, fbf);
  if (t == 0) storeF(out, NG * DH + DIN, logf(g), fbf);
}

// agg[dst[e]][d] += h[src[e]][d]
__global__ void k_scatter(const void* __restrict__ ei, const void* __restrict__ h,
                          float* __restrict__ agg, const int* __restrict__ flags,
                          int dshift, int total) {
  int fbf = flags[0], i64 = flags[1];
  int i = blockIdx.x * blockDim.x + threadIdx.x;
  int stride = gridDim.x * blockDim.x;
  int dmask = (1 << dshift) - 1;
  for (; i < total; i += stride) {
    int e = i >> dshift;
    int d = i & dmask;
    int s = loadI(ei, e, i64);
    int t2 = loadI(ei, (long)NE + e, i64);
    s = min(max(s, 0), NN - 1);
    t2 = min(max(t2, 0), NN - 1);
    atomicAdd(&agg[((long)t2 << dshift) + d], loadF(h, ((long)s << dshift) + d, fbf));
  }
}

// hout[n][j] = relu( sum_k agg[n][k]*Wrel[k][j] + sum_k hin[n][k]*Wroot[k][j] + b[j] )
__global__ void k_gconv(const float* __restrict__ agg, const void* __restrict__ hin,
                        const void* __restrict__ Wrel, const void* __restrict__ Wroot,
                        const void* __restrict__ bias, void* __restrict__ hout,
                        const int* __restrict__ flags, int K) {
  __shared__ float s_agg[DH];
  __shared__ float s_h[DH];
  int fbf = flags[0];
  int n = blockIdx.x;
  int j = threadIdx.x;
  if (j < K) {
    s_agg[j] = agg[(long)n * K + j];
    s_h[j] = loadF(hin, (long)n * K + j, fbf);
  }
  __syncthreads();
  float acc = loadF(bias, j, fbf);
  for (int k = 0; k < K; ++k) {
    acc += s_agg[k] * loadF(Wrel, (long)k * DH + j, fbf);
    acc += s_h[k] * loadF(Wroot, (long)k * DH + j, fbf);
  }
  storeF(hout, (long)n * DH + j, fmaxf(acc, 0.f), fbf);
}

__global__ void k_counts(const void* __restrict__ batch, float* __restrict__ counts,
                         const int* __restrict__ flags) {
  int i64 = flags[1];
  int n = blockIdx.x * blockDim.x + threadIdx.x;
  if (n < NN) {
    int b = loadI(batch, n, i64);
    b = min(max(b, 0), NG - 1);
    atomicAdd(&counts[b], 1.0f);
  }
}

__global__ void k_pool(const void* __restrict__ batch, const void* __restrict__ h,
                       float* __restrict__ pooled, const int* __restrict__ flags) {
  int fbf = flags[0], i64 = flags[1];
  int i = blockIdx.x * blockDim.x + threadIdx.x;
  int stride = gridDim.x * blockDim.x;
  for (; i < NN * DH; i += stride) {
    int n = i >> 8;
    int j = i & 255;
    int b = loadI(batch, n, i64);
    b = min(max(b, 0), NG - 1);
    atomicAdd(&pooled[(b << 8) + j], loadF(h, i, fbf));
  }
}

__global__ void k_finalize(const float* __restrict__ pooled, const float* __restrict__ counts,
                           void* __restrict__ out, const int* __restrict__ flags) {
  int fbf = flags[0];
  int i = blockIdx.x * blockDim.x + threadIdx.x;  // 64 blocks * 256
  int g = i >> 8;
  storeF(out, i, pooled[i] / fmaxf(counts[g], 1.0f), fbf);
}

extern "C" void kernel_launch(void* const* d_in, const int* in_sizes, int n_in,
                              void* d_out, int out_size, void* d_ws, size_t ws_size,
                              hipStream_t stream) {
  const void* x = d_in[0];
  const void* ei = d_in[1];
  const void* batch = d_in[2];
  const void* W1r = d_in[3];
  const void* W1o = d_in[4];
  const void* b1 = d_in[5];
  const void* W2r = d_in[6];
  const void* W2o = d_in[7];
  const void* b2 = d_in[8];
  void* out = d_out;

  // workspace layout
  int* flags = (int*)d_ws;                  // 16 ints
  float* agg = (float*)d_ws + 16;           // NN*DH f32
  float* colsum = agg + NN * DH;            // DIN
  float* pooled = colsum + DIN;             // NG*DH
  float* counts = pooled + NG * DH;         // NG
  void* h = (void*)(counts + NG);           // NN*DH elems, stored in detected float dtype

  const int zero_all = NN * DH + DIN + NG * DH + NG;

  k_detect<<<1, 256, 0, stream>>>(x, ei, flags);
  k_zero<<<4096, 256, 0, stream>>>(agg, zero_all);

  // handcrafted head
  k_colsum<<<512, 128, 0, stream>>>(x, colsum, flags);
  k_handcrafted<<<1, 128, 0, stream>>>(colsum, out, flags);

  // layer 1 (K = 128)
  k_scatter<<<8192, 256, 0, stream>>>(ei, x, agg, flags, 7, NE * DIN);
  k_gconv<<<NN, 256, 0, stream>>>(agg, x, W1r, W1o, b1, h, flags, DIN);

  // layer 2 (K = 256), h updated in-place (row n read fully into LDS before write)
  k_zero<<<4096, 256, 0, stream>>>(agg, NN * DH);
  k_scatter<<<8192, 256, 0, stream>>>(ei, h, agg, flags, 8, NE * DH);
  k_gconv<<<NN, 256, 0, stream>>>(agg, h, W2r, W2o, b2, h, flags, DH);

  // layer 3 (K = 256, shared weights)
  k_zero<<<4096, 256, 0, stream>>>(agg, NN * DH);
  k_scatter<<<8192, 256, 0, stream>>>(ei, h, agg, flags, 8, NE * DH);
  k_gconv<<<NN, 256, 0, stream>>>(agg, h, W2r, W2o, b2, h, flags, DH);

  // mean pool
  k_counts<<<(NN + 255) / 256, 256, 0, stream>>>(batch, counts, flags);
  k_pool<<<4096, 256, 0, stream>>>(batch, h, pooled, flags);
  k_finalize<<<NG, 256, 0, stream>>>(pooled, counts, out, flags);
}

// Round 3
// 864.579 us; speedup vs baseline: 5.1513x; 5.1513x over previous
//
#include <hip/hip_runtime.h>
#include <hip/hip_bf16.h>
#include <string.h>

#define NN 50000
#define NE 800000
#define DIN 128
#define DH 256
#define NG 64

typedef short bf16x8 __attribute__((ext_vector_type(8)));
typedef float f32x4 __attribute__((ext_vector_type(4)));

__device__ __forceinline__ float bf2f(__hip_bfloat16 v) { return __bfloat162float(v); }
__device__ __forceinline__ float bfbits(unsigned int lo16) {
  unsigned int u = lo16 << 16;
  float f;
  memcpy(&f, &u, 4);
  return f;
}

// flag-driven generic accessors: fbf=1 -> floats stored as bf16; i64=1 -> ints stored as int64
__device__ __forceinline__ float loadF(const void* p, long i, int fbf) {
  return fbf ? bf2f(((const __hip_bfloat16*)p)[i]) : ((const float*)p)[i];
}
__device__ __forceinline__ void storeF(void* p, long i, float v, int fbf) {
  if (fbf) ((__hip_bfloat16*)p)[i] = __float2bfloat16(v);
  else ((float*)p)[i] = v;
}
__device__ __forceinline__ int loadI(const void* p, long i, int i64) {
  return i64 ? (int)((const long long*)p)[i] : ((const int*)p)[i];
}

__global__ void k_detect(const void* x, const void* ei, int* flags) {
  __shared__ int s_f32sig, s_i32sig;
  if (threadIdx.x == 0) { s_f32sig = 0; s_i32sig = 0; }
  __syncthreads();
  int t = threadIdx.x;
  const unsigned short* u = (const unsigned short*)x;
  int f = 0;
  for (int i = 2 * t; i < 8192; i += 512) if (u[i] >= 0x4000) f = 1;
  const unsigned int* w = (const unsigned int*)ei;
  int g = 0;
  for (int i = 2 * t + 1; i < 8192; i += 512) if (w[i] != 0u) g = 1;
  if (f) atomicOr(&s_f32sig, 1);
  if (g) atomicOr(&s_i32sig, 1);
  __syncthreads();
  if (t == 0) { flags[0] = s_f32sig ? 0 : 1; flags[1] = s_i32sig ? 0 : 1; }
}

__global__ void k_zero(int* __restrict__ p, int n) {
  int i = blockIdx.x * blockDim.x + threadIdx.x;
  int stride = gridDim.x * blockDim.x;
  for (; i < n; i += stride) p[i] = 0;
}

__global__ void k_colsum(const void* __restrict__ x, float* __restrict__ colsum,
                         const int* __restrict__ flags) {
  int fbf = flags[0];
  int col = threadIdx.x;  // 0..127
  float acc = 0.f;
  for (int r = blockIdx.x; r < NN; r += gridDim.x)
    acc += loadF(x, (long)r * DIN + col, fbf);
  atomicAdd(&colsum[col], acc);
}

__global__ void k_handcrafted(const float* __restrict__ colsum, void* __restrict__ out,
                              const int* __restrict__ flags) {
  __shared__ float s[DIN];
  int fbf = flags[0];
  int t = threadIdx.x;
  s[t] = colsum[t];
  __syncthreads();
  for (int off = DIN / 2; off > 0; off >>= 1) {
    if (t < off) s[t] += s[t + off];
    __syncthreads();
  }
  float g = s[0];
  storeF(out, NG * DH + t, colsum[t] / g, fbf);
  if (t == 0) storeF(out, NG * DH + DIN, logf(g), fbf);
}

// convert x (whatever float dtype) -> bf16 copy
__global__ void k_convert(const void* __restrict__ x, __hip_bfloat16* __restrict__ xb,
                          const int* __restrict__ flags, int n) {
  int fbf = flags[0];
  int i = blockIdx.x * blockDim.x + threadIdx.x;
  int stride = gridDim.x * blockDim.x;
  for (; i < n; i += stride) xb[i] = __float2bfloat16(loadF(x, i, fbf));
}

// pack weights into MFMA b-frag order:
// pack[m*K*DH + ((ct*KS + ks)*64 + l)*8 + j] = W_m[(ks*32 + (l>>4)*8 + j)*DH + ct*16 + (l&15)]
__global__ void k_pack_w(const void* __restrict__ Wrel, const void* __restrict__ Wroot,
                         const void* __restrict__ bias, __hip_bfloat16* __restrict__ pack,
                         float* __restrict__ biasf, const int* __restrict__ flags, int K) {
  int fbf = flags[0];
  int KS = K >> 5;
  int total = 2 * K * DH;
  int i = blockIdx.x * blockDim.x + threadIdx.x;
  int stride = gridDim.x * blockDim.x;
  for (int p = i; p < total; p += stride) {
    int m = p / (K * DH);
    int r = p % (K * DH);
    int j = r & 7;
    int l = (r >> 3) & 63;
    int q2 = r >> 9;       // ct*KS + ks
    int ks = q2 % KS;
    int ct = q2 / KS;
    int kk = ks * 32 + (l >> 4) * 8 + j;
    int col = ct * 16 + (l & 15);
    const void* W = m ? Wroot : Wrel;
    pack[p] = __float2bfloat16(loadF(W, (long)kk * DH + col, fbf));
  }
  if (i < DH) biasf[i] = loadF(bias, i, fbf);
}

// ---------- CSR build ----------
__global__ void k_deg(const void* __restrict__ ei, int* __restrict__ cnt,
                      const int* __restrict__ flags) {
  int i64 = flags[1];
  int e = blockIdx.x * blockDim.x + threadIdx.x;
  int stride = gridDim.x * blockDim.x;
  for (; e < NE; e += stride) {
    int d = loadI(ei, (long)NE + e, i64);
    d = min(max(d, 0), NN - 1);
    atomicAdd(&cnt[d], 1);
  }
}

#define SCAN_B 256
__global__ void k_scan1(const int* __restrict__ cnt, int* __restrict__ rowptr,
                        int* __restrict__ bsum) {
  __shared__ int s[SCAN_B];
  int b = blockIdx.x, t = threadIdx.x;
  int i = b * SCAN_B + t;
  int v = (i < NN) ? cnt[i] : 0;
  s[t] = v;
  __syncthreads();
  for (int off = 1; off < SCAN_B; off <<= 1) {
    int xv = (t >= off) ? s[t - off] : 0;
    __syncthreads();
    s[t] += xv;
    __syncthreads();
  }
  if (i < NN) rowptr[i] = s[t] - v;
  if (t == SCAN_B - 1) bsum[b] = s[t];
}

__global__ void k_scan2(int* __restrict__ bsum, int nb) {
  __shared__ int s[SCAN_B];
  int t = threadIdx.x;
  int v = (t < nb) ? bsum[t] : 0;
  s[t] = v;
  __syncthreads();
  for (int off = 1; off < SCAN_B; off <<= 1) {
    int xv = (t >= off) ? s[t - off] : 0;
    __syncthreads();
    s[t] += xv;
    __syncthreads();
  }
  if (t < nb) bsum[t] = s[t] - v;  // exclusive
}

__global__ void k_scan3(int* __restrict__ rowptr, const int* __restrict__ bsum) {
  int i = blockIdx.x * blockDim.x + threadIdx.x;
  int stride = gridDim.x * blockDim.x;
  for (; i < NN; i += stride) rowptr[i] += bsum[i >> 8];
  if (blockIdx.x == 0 && threadIdx.x == 0) rowptr[NN] = NE;
}

__global__ void k_fill(const void* __restrict__ ei, const int* __restrict__ rowptr,
                       int* __restrict__ cur, int* __restrict__ srcs,
                       const int* __restrict__ flags) {
  int i64 = flags[1];
  int e = blockIdx.x * blockDim.x + threadIdx.x;
  int stride = gridDim.x * blockDim.x;
  for (; e < NE; e += stride) {
    int s = loadI(ei, e, i64);
    int d = loadI(ei, (long)NE + e, i64);
    s = min(max(s, 0), NN - 1);
    d = min(max(d, 0), NN - 1);
    int p = atomicAdd(&cur[d], 1);
    srcs[rowptr[d] + p] = s;
  }
}

// agg[n][:] = sum_{e in CSR[n]} h[srcs[e]][:]   (f32 accum, bf16 out)
// blockDim = D/2, each thread handles 2 adjacent cols via 4B loads
__global__ void k_gather(const int* __restrict__ rowptr, const int* __restrict__ srcs,
                         const __hip_bfloat16* __restrict__ h, __hip_bfloat16* __restrict__ agg,
                         int D) {
  int n = blockIdx.x;
  int j = threadIdx.x;  // 0..D/2-1
  int half = D >> 1;
  int beg = rowptr[n], end = rowptr[n + 1];
  const unsigned int* h2 = (const unsigned int*)h;
  float a0 = 0.f, a1 = 0.f;
  for (int i = beg; i < end; ++i) {
    unsigned int v = h2[srcs[i] * half + j];
    a0 += bfbits(v & 0xffffu);
    a1 += bfbits(v >> 16);
  }
  agg[n * D + 2 * j] = __float2bfloat16(a0);
  agg[n * D + 2 * j + 1] = __float2bfloat16(a1);
}

// out[n][:] = relu(A1[n][:] @ Wrel + A2[n][:] @ Wroot + bias)
// block: 64 rows x 256 cols, 4 waves; wave w covers cols [64w, 64w+64)
__global__ __launch_bounds__(256) void k_gemm(
    const __hip_bfloat16* __restrict__ A1, const __hip_bfloat16* __restrict__ A2,
    const __hip_bfloat16* __restrict__ Wpack, const float* __restrict__ bias,
    __hip_bfloat16* __restrict__ out, int K) {
  int KS = K >> 5;
  int lane = threadIdx.x & 63;
  int wave = threadIdx.x >> 6;
  int m15 = lane & 15;
  int q = lane >> 4;
  int row0 = blockIdx.x * 64;
  const short* A1s = (const short*)A1;
  const short* A2s = (const short*)A2;
  const short* Wp = (const short*)Wpack;
  int wrootOfs = K * DH;  // elems: second packed matrix
  f32x4 acc[4][4] = {};
  for (int ks = 0; ks < KS; ++ks) {
    int kofs = ks * 32 + q * 8;
    bf16x8 a1[4], a2[4], b1[4], b2[4];
#pragma unroll
    for (int mt = 0; mt < 4; ++mt) {
      int r = row0 + mt * 16 + m15;
      if (r > NN - 1) r = NN - 1;
      a1[mt] = *(const bf16x8*)(A1s + r * K + kofs);
      a2[mt] = *(const bf16x8*)(A2s + r * K + kofs);
    }
#pragma unroll
    for (int ct = 0; ct < 4; ++ct) {
      int gct = wave * 4 + ct;
      const short* base = Wp + ((gct * KS + ks) * 64 + lane) * 8;
      b1[ct] = *(const bf16x8*)(base);
      b2[ct] = *(const bf16x8*)(base + wrootOfs);
    }
#pragma unroll
    for (int mt = 0; mt < 4; ++mt)
#pragma unroll
      for (int ct = 0; ct < 4; ++ct) {
        acc[mt][ct] = __builtin_amdgcn_mfma_f32_16x16x32_bf16(a1[mt], b1[ct], acc[mt][ct], 0, 0, 0);
        acc[mt][ct] = __builtin_amdgcn_mfma_f32_16x16x32_bf16(a2[mt], b2[ct], acc[mt][ct], 0, 0, 0);
      }
  }
#pragma unroll
  for (int mt = 0; mt < 4; ++mt)
#pragma unroll
    for (int ct = 0; ct < 4; ++ct) {
      int col = wave * 64 + ct * 16 + m15;
      float bv = bias[col];
#pragma unroll
      for (int r = 0; r < 4; ++r) {
        int row = row0 + mt * 16 + q * 4 + r;
        if (row < NN) {
          float v = acc[mt][ct][r] + bv;
          out[row * DH + col] = __float2bfloat16(fmaxf(v, 0.f));
        }
      }
    }
}

// ---------- pooling ----------
__global__ void k_counts(const void* __restrict__ batch, float* __restrict__ counts,
                         const int* __restrict__ flags) {
  int i64 = flags[1];
  int n = blockIdx.x * blockDim.x + threadIdx.x;
  if (n < NN) {
    int b = loadI(batch, n, i64);
    b = min(max(b, 0), NG - 1);
    atomicAdd(&counts[b], 1.0f);
  }
}

__global__ void k_pool(const void* __restrict__ batch, const __hip_bfloat16* __restrict__ h,
                       float* __restrict__ pooled, const int* __restrict__ flags) {
  int i64 = flags[1];
  int i = blockIdx.x * blockDim.x + threadIdx.x;
  int stride = gridDim.x * blockDim.x;
  for (; i < NN * DH; i += stride) {
    int n = i >> 8;
    int j = i & 255;
    int b = loadI(batch, n, i64);
    b = min(max(b, 0), NG - 1);
    atomicAdd(&pooled[(b << 8) + j], bf2f(h[i]));
  }
}

__global__ void k_finalize(const float* __restrict__ pooled, const float* __restrict__ counts,
                           void* __restrict__ out, const int* __restrict__ flags) {
  int fbf = flags[0];
  int i = blockIdx.x * blockDim.x + threadIdx.x;  // 64 blocks * 256
  int g = i >> 8;
  storeF(out, i, pooled[i] / fmaxf(counts[g], 1.0f), fbf);
}

extern "C" void kernel_launch(void* const* d_in, const int* in_sizes, int n_in,
                              void* d_out, int out_size, void* d_ws, size_t ws_size,
                              hipStream_t stream) {
  const void* x = d_in[0];
  const void* ei = d_in[1];
  const void* batch = d_in[2];
  const void* W1r = d_in[3];
  const void* W1o = d_in[4];
  const void* b1 = d_in[5];
  const void* W2r = d_in[6];
  const void* W2o = d_in[7];
  const void* b2 = d_in[8];
  void* out = d_out;

  // ---- workspace layout (256B-aligned chunks) ----
  char* w = (char*)d_ws;
  auto alloc = [&](size_t bytes) -> char* {
    char* p = w;
    w += (bytes + 255) & ~(size_t)255;
    return p;
  };
  int* flags = (int*)alloc(64);
  // contiguous zero region: cnt, cur, colsum, pooled, counts
  const int zero_n = NN + NN + DIN + NG * DH + NG;
  int* zreg = (int*)alloc((size_t)zero_n * 4);
  int* cnt = zreg;
  int* cur = cnt + NN;
  float* colsum = (float*)(cur + NN);
  float* pooled = colsum + DIN;
  float* counts = pooled + NG * DH;
  int* rowptr = (int*)alloc((NN + 1) * 4);
  int* bsum = (int*)alloc(SCAN_B * 4);
  int* srcs = (int*)alloc((size_t)NE * 4);
  __hip_bfloat16* xb = (__hip_bfloat16*)alloc((size_t)NN * DIN * 2);
  __hip_bfloat16* aggb = (__hip_bfloat16*)alloc((size_t)NN * DH * 2);
  __hip_bfloat16* h = (__hip_bfloat16*)alloc((size_t)NN * DH * 2);
  __hip_bfloat16* wp1 = (__hip_bfloat16*)alloc((size_t)2 * DIN * DH * 2);
  __hip_bfloat16* wp2 = (__hip_bfloat16*)alloc((size_t)2 * DH * DH * 2);
  float* b1f = (float*)alloc(DH * 4);
  float* b2f = (float*)alloc(DH * 4);

  const int nblk = (NN + SCAN_B - 1) / SCAN_B;  // 196
  const int gemm_grid = (NN + 63) / 64;          // 782

  k_detect<<<1, 256, 0, stream>>>(x, ei, flags);
  k_zero<<<512, 256, 0, stream>>>(zreg, zero_n);

  // weight packing + x conversion + handcrafted head
  k_pack_w<<<64, 256, 0, stream>>>(W1r, W1o, b1, wp1, b1f, flags, DIN);
  k_pack_w<<<128, 256, 0, stream>>>(W2r, W2o, b2, wp2, b2f, flags, DH);
  k_convert<<<2048, 256, 0, stream>>>(x, xb, flags, NN * DIN);
  k_colsum<<<512, 128, 0, stream>>>(x, colsum, flags);
  k_handcrafted<<<1, 128, 0, stream>>>(colsum, out, flags);

  // CSR build (once; reused by all 3 layers)
  k_deg<<<1024, 256, 0, stream>>>(ei, cnt, flags);
  k_scan1<<<nblk, SCAN_B, 0, stream>>>(cnt, rowptr, bsum);
  k_scan2<<<1, SCAN_B, 0, stream>>>(bsum, nblk);
  k_scan3<<<256, 256, 0, stream>>>(rowptr, bsum);
  k_fill<<<1024, 256, 0, stream>>>(ei, rowptr, cur, srcs, flags);

  // layer 1 (K = 128)
  k_gather<<<NN, DIN / 2, 0, stream>>>(rowptr, srcs, xb, aggb, DIN);
  k_gemm<<<gemm_grid, 256, 0, stream>>>(aggb, xb, wp1, b1f, h, DIN);
  // layer 2 (K = 256), h in-place (each block reads only rows it writes)
  k_gather<<<NN, DH / 2, 0, stream>>>(rowptr, srcs, h, aggb, DH);
  k_gemm<<<gemm_grid, 256, 0, stream>>>(aggb, h, wp2, b2f, h, DH);
  // layer 3 (K = 256, shared weights)
  k_gather<<<NN, DH / 2, 0, stream>>>(rowptr, srcs, h, aggb, DH);
  k_gemm<<<gemm_grid, 256, 0, stream>>>(aggb, h, wp2, b2f, h, DH);

  // mean pool
  k_counts<<<nblk, 256, 0, stream>>>(batch, counts, flags);
  k_pool<<<4096, 256, 0, stream>>>(batch, h, pooled, flags);
  k_finalize<<<NG, 256, 0, stream>>>(pooled, counts, out, flags);
}

// Round 4
// 801.238 us; speedup vs baseline: 5.5585x; 1.0791x over previous
//
#include <hip/hip_runtime.h>
#include <hip/hip_bf16.h>
#include <string.h>

#define NN 50000
#define NE 800000
#define DIN 128
#define DH 256
#define NG 64

typedef short bf16x8 __attribute__((ext_vector_type(8)));
typedef float f32x4 __attribute__((ext_vector_type(4)));

__device__ __forceinline__ float bf2f(__hip_bfloat16 v) { return __bfloat162float(v); }
__device__ __forceinline__ float bfbits(unsigned int lo16) {
  unsigned int u = lo16 << 16;
  float f;
  memcpy(&f, &u, 4);
  return f;
}

// flag-driven generic accessors: fbf=1 -> floats stored as bf16; i64=1 -> ints stored as int64
__device__ __forceinline__ float loadF(const void* p, long i, int fbf) {
  return fbf ? bf2f(((const __hip_bfloat16*)p)[i]) : ((const float*)p)[i];
}
__device__ __forceinline__ void storeF(void* p, long i, float v, int fbf) {
  if (fbf) ((__hip_bfloat16*)p)[i] = __float2bfloat16(v);
  else ((float*)p)[i] = v;
}
__device__ __forceinline__ int loadI(const void* p, long i, int i64) {
  return i64 ? (int)((const long long*)p)[i] : ((const int*)p)[i];
}

__global__ void k_detect(const void* x, const void* ei, int* flags) {
  __shared__ int s_f32sig, s_i32sig;
  if (threadIdx.x == 0) { s_f32sig = 0; s_i32sig = 0; }
  __syncthreads();
  int t = threadIdx.x;
  const unsigned short* u = (const unsigned short*)x;
  int f = 0;
  for (int i = 2 * t; i < 8192; i += 512) if (u[i] >= 0x4000) f = 1;
  const unsigned int* w = (const unsigned int*)ei;
  int g = 0;
  for (int i = 2 * t + 1; i < 8192; i += 512) if (w[i] != 0u) g = 1;
  if (f) atomicOr(&s_f32sig, 1);
  if (g) atomicOr(&s_i32sig, 1);
  __syncthreads();
  if (t == 0) { flags[0] = s_f32sig ? 0 : 1; flags[1] = s_i32sig ? 0 : 1; }
}

__global__ void k_zero(int* __restrict__ p, int n) {
  int i = blockIdx.x * blockDim.x + threadIdx.x;
  int stride = gridDim.x * blockDim.x;
  for (; i < n; i += stride) p[i] = 0;
}

__global__ void k_colsum(const void* __restrict__ x, float* __restrict__ colsum,
                         const int* __restrict__ flags) {
  int fbf = flags[0];
  int col = threadIdx.x;  // 0..127
  float acc = 0.f;
  for (int r = blockIdx.x; r < NN; r += gridDim.x)
    acc += loadF(x, (long)r * DIN + col, fbf);
  atomicAdd(&colsum[col], acc);
}

__global__ void k_handcrafted(const float* __restrict__ colsum, void* __restrict__ out,
                              const int* __restrict__ flags) {
  __shared__ float s[DIN];
  int fbf = flags[0];
  int t = threadIdx.x;
  s[t] = colsum[t];
  __syncthreads();
  for (int off = DIN / 2; off > 0; off >>= 1) {
    if (t < off) s[t] += s[t + off];
    __syncthreads();
  }
  float g = s[0];
  storeF(out, NG * DH + t, colsum[t] / g, fbf);
  if (t == 0) storeF(out, NG * DH + DIN, logf(g), fbf);
}

// convert x (whatever float dtype) -> bf16 copy
__global__ void k_convert(const void* __restrict__ x, __hip_bfloat16* __restrict__ xb,
                          const int* __restrict__ flags, int n) {
  int fbf = flags[0];
  int i = blockIdx.x * blockDim.x + threadIdx.x;
  int stride = gridDim.x * blockDim.x;
  for (; i < n; i += stride) xb[i] = __float2bfloat16(loadF(x, i, fbf));
}

// pack weights into MFMA b-frag order:
// pack[m*K*DH + ((ct*KS + ks)*64 + l)*8 + j] = W_m[(ks*32 + (l>>4)*8 + j)*DH + ct*16 + (l&15)]
__global__ void k_pack_w(const void* __restrict__ Wrel, const void* __restrict__ Wroot,
                         const void* __restrict__ bias, __hip_bfloat16* __restrict__ pack,
                         float* __restrict__ biasf, const int* __restrict__ flags, int K) {
  int fbf = flags[0];
  int KS = K >> 5;
  int total = 2 * K * DH;
  int i = blockIdx.x * blockDim.x + threadIdx.x;
  int stride = gridDim.x * blockDim.x;
  for (int p = i; p < total; p += stride) {
    int m = p / (K * DH);
    int r = p % (K * DH);
    int j = r & 7;
    int l = (r >> 3) & 63;
    int q2 = r >> 9;       // ct*KS + ks
    int ks = q2 % KS;
    int ct = q2 / KS;
    int kk = ks * 32 + (l >> 4) * 8 + j;
    int col = ct * 16 + (l & 15);
    const void* W = m ? Wroot : Wrel;
    pack[p] = __float2bfloat16(loadF(W, (long)kk * DH + col, fbf));
  }
  if (i < DH) biasf[i] = loadF(bias, i, fbf);
}

// ---------- CSR build ----------
__global__ void k_deg(const void* __restrict__ ei, int* __restrict__ cnt,
                      const int* __restrict__ flags) {
  int i64 = flags[1];
  int e = blockIdx.x * blockDim.x + threadIdx.x;
  int stride = gridDim.x * blockDim.x;
  for (; e < NE; e += stride) {
    int d = loadI(ei, (long)NE + e, i64);
    d = min(max(d, 0), NN - 1);
    atomicAdd(&cnt[d], 1);
  }
}

#define SCAN_B 256
__global__ void k_scan1(const int* __restrict__ cnt, int* __restrict__ rowptr,
                        int* __restrict__ bsum) {
  __shared__ int s[SCAN_B];
  int b = blockIdx.x, t = threadIdx.x;
  int i = b * SCAN_B + t;
  int v = (i < NN) ? cnt[i] : 0;
  s[t] = v;
  __syncthreads();
  for (int off = 1; off < SCAN_B; off <<= 1) {
    int xv = (t >= off) ? s[t - off] : 0;
    __syncthreads();
    s[t] += xv;
    __syncthreads();
  }
  if (i < NN) rowptr[i] = s[t] - v;
  if (t == SCAN_B - 1) bsum[b] = s[t];
}

__global__ void k_scan2(int* __restrict__ bsum, int nb) {
  __shared__ int s[SCAN_B];
  int t = threadIdx.x;
  int v = (t < nb) ? bsum[t] : 0;
  s[t] = v;
  __syncthreads();
  for (int off = 1; off < SCAN_B; off <<= 1) {
    int xv = (t >= off) ? s[t - off] : 0;
    __syncthreads();
    s[t] += xv;
    __syncthreads();
  }
  if (t < nb) bsum[t] = s[t] - v;  // exclusive
}

__global__ void k_scan3(int* __restrict__ rowptr, const int* __restrict__ bsum) {
  int i = blockIdx.x * blockDim.x + threadIdx.x;
  int stride = gridDim.x * blockDim.x;
  for (; i < NN; i += stride) rowptr[i] += bsum[i >> 8];
  if (blockIdx.x == 0 && threadIdx.x == 0) rowptr[NN] = NE;
}

__global__ void k_fill(const void* __restrict__ ei, const int* __restrict__ rowptr,
                       int* __restrict__ cur, int* __restrict__ srcs,
                       const int* __restrict__ flags) {
  int i64 = flags[1];
  int e = blockIdx.x * blockDim.x + threadIdx.x;
  int stride = gridDim.x * blockDim.x;
  for (; e < NE; e += stride) {
    int s = loadI(ei, e, i64);
    int d = loadI(ei, (long)NE + e, i64);
    s = min(max(s, 0), NN - 1);
    d = min(max(d, 0), NN - 1);
    int p = atomicAdd(&cur[d], 1);
    srcs[rowptr[d] + p] = s;
  }
}

// agg[n][:] = sum_{e in CSR[n]} h[srcs[e]][:]   (f32 accum, bf16 out)
// blockDim = D/2, each thread handles 2 adjacent cols via 4B loads
__global__ void k_gather(const int* __restrict__ rowptr, const int* __restrict__ srcs,
                         const __hip_bfloat16* __restrict__ h, __hip_bfloat16* __restrict__ agg,
                         int D) {
  int n = blockIdx.x;
  int j = threadIdx.x;  // 0..D/2-1
  int half = D >> 1;
  int beg = rowptr[n], end = rowptr[n + 1];
  const unsigned int* h2 = (const unsigned int*)h;
  float a0 = 0.f, a1 = 0.f;
  for (int i = beg; i < end; ++i) {
    unsigned int v = h2[srcs[i] * half + j];
    a0 += bfbits(v & 0xffffu);
    a1 += bfbits(v >> 16);
  }
  agg[n * D + 2 * j] = __float2bfloat16(a0);
  agg[n * D + 2 * j + 1] = __float2bfloat16(a1);
}

// out[n][:] = relu(A1[n][:] @ Wrel + A2[n][:] @ Wroot + bias)
// block: 64 rows x 256 cols, 4 waves; wave w covers cols [64w, 64w+64)
__global__ __launch_bounds__(256) void k_gemm(
    const __hip_bfloat16* __restrict__ A1, const __hip_bfloat16* __restrict__ A2,
    const __hip_bfloat16* __restrict__ Wpack, const float* __restrict__ bias,
    __hip_bfloat16* __restrict__ out, int K) {
  int KS = K >> 5;
  int lane = threadIdx.x & 63;
  int wave = threadIdx.x >> 6;
  int m15 = lane & 15;
  int q = lane >> 4;
  int row0 = blockIdx.x * 64;
  const short* A1s = (const short*)A1;
  const short* A2s = (const short*)A2;
  const short* Wp = (const short*)Wpack;
  int wrootOfs = K * DH;  // elems: second packed matrix
  f32x4 acc[4][4] = {};
  for (int ks = 0; ks < KS; ++ks) {
    int kofs = ks * 32 + q * 8;
    bf16x8 a1[4], a2[4], b1[4], b2[4];
#pragma unroll
    for (int mt = 0; mt < 4; ++mt) {
      int r = row0 + mt * 16 + m15;
      if (r > NN - 1) r = NN - 1;
      a1[mt] = *(const bf16x8*)(A1s + r * K + kofs);
      a2[mt] = *(const bf16x8*)(A2s + r * K + kofs);
    }
#pragma unroll
    for (int ct = 0; ct < 4; ++ct) {
      int gct = wave * 4 + ct;
      const short* base = Wp + ((gct * KS + ks) * 64 + lane) * 8;
      b1[ct] = *(const bf16x8*)(base);
      b2[ct] = *(const bf16x8*)(base + wrootOfs);
    }
#pragma unroll
    for (int mt = 0; mt < 4; ++mt)
#pragma unroll
      for (int ct = 0; ct < 4; ++ct) {
        acc[mt][ct] = __builtin_amdgcn_mfma_f32_16x16x32_bf16(a1[mt], b1[ct], acc[mt][ct], 0, 0, 0);
        acc[mt][ct] = __builtin_amdgcn_mfma_f32_16x16x32_bf16(a2[mt], b2[ct], acc[mt][ct], 0, 0, 0);
      }
  }
#pragma unroll
  for (int mt = 0; mt < 4; ++mt)
#pragma unroll
    for (int ct = 0; ct < 4; ++ct) {
      int col = wave * 64 + ct * 16 + m15;
      float bv = bias[col];
#pragma unroll
      for (int r = 0; r < 4; ++r) {
        int row = row0 + mt * 16 + q * 4 + r;
        if (row < NN) {
          float v = acc[mt][ct][r] + bv;
          out[row * DH + col] = __float2bfloat16(fmaxf(v, 0.f));
        }
      }
    }
}

// ---------- pooling (batch is sorted -> segment bounds, no atomics) ----------
__global__ void k_bounds(const void* __restrict__ batch, int* __restrict__ gstart,
                         int* __restrict__ gend, const int* __restrict__ flags) {
  int i64 = flags[1];
  int n = blockIdx.x * blockDim.x + threadIdx.x;
  if (n >= NN) return;
  int b = min(max(loadI(batch, n, i64), 0), NG - 1);
  int bp = (n == 0) ? -1 : min(max(loadI(batch, n - 1, i64), 0), NG - 1);
  if (b != bp) gstart[b] = n;
  int bn = (n == NN - 1) ? -1 : min(max(loadI(batch, n + 1, i64), 0), NG - 1);
  if (b != bn) gend[b] = n + 1;
}

// one block per graph; thread j sums column j over the graph's row range
__global__ void k_poolseg(const int* __restrict__ gstart, const int* __restrict__ gend,
                          const __hip_bfloat16* __restrict__ h, void* __restrict__ out,
                          const int* __restrict__ flags) {
  int fbf = flags[0];
  int g = blockIdx.x;
  int j = threadIdx.x;
  int s = gstart[g], e = gend[g];
  float acc = 0.f;
  for (int r = s; r < e; ++r) acc += bf2f(h[(long)r * DH + j]);
  float cnt = fmaxf((float)(e - s), 1.0f);
  storeF(out, (long)g * DH + j, acc / cnt, fbf);
}

extern "C" void kernel_launch(void* const* d_in, const int* in_sizes, int n_in,
                              void* d_out, int out_size, void* d_ws, size_t ws_size,
                              hipStream_t stream) {
  const void* x = d_in[0];
  const void* ei = d_in[1];
  const void* batch = d_in[2];
  const void* W1r = d_in[3];
  const void* W1o = d_in[4];
  const void* b1 = d_in[5];
  const void* W2r = d_in[6];
  const void* W2o = d_in[7];
  const void* b2 = d_in[8];
  void* out = d_out;

  // ---- workspace layout (256B-aligned chunks) ----
  char* w = (char*)d_ws;
  auto alloc = [&](size_t bytes) -> char* {
    char* p = w;
    w += (bytes + 255) & ~(size_t)255;
    return p;
  };
  int* flags = (int*)alloc(64);
  // contiguous zero region: cnt, cur, colsum, gstart, gend
  const int zero_n = NN + NN + DIN + NG + NG;
  int* zreg = (int*)alloc((size_t)zero_n * 4);
  int* cnt = zreg;
  int* cur = cnt + NN;
  float* colsum = (float*)(cur + NN);
  int* gstart = (int*)(colsum + DIN);
  int* gend = gstart + NG;
  int* rowptr = (int*)alloc((NN + 1) * 4);
  int* bsum = (int*)alloc(SCAN_B * 4);
  int* srcs = (int*)alloc((size_t)NE * 4);
  __hip_bfloat16* xb = (__hip_bfloat16*)alloc((size_t)NN * DIN * 2);
  __hip_bfloat16* aggb = (__hip_bfloat16*)alloc((size_t)NN * DH * 2);
  __hip_bfloat16* h = (__hip_bfloat16*)alloc((size_t)NN * DH * 2);
  __hip_bfloat16* wp1 = (__hip_bfloat16*)alloc((size_t)2 * DIN * DH * 2);
  __hip_bfloat16* wp2 = (__hip_bfloat16*)alloc((size_t)2 * DH * DH * 2);
  float* b1f = (float*)alloc(DH * 4);
  float* b2f = (float*)alloc(DH * 4);

  const int nblk = (NN + SCAN_B - 1) / SCAN_B;  // 196
  const int gemm_grid = (NN + 63) / 64;          // 782

  k_detect<<<1, 256, 0, stream>>>(x, ei, flags);
  k_zero<<<512, 256, 0, stream>>>(zreg, zero_n);

  // weight packing + x conversion + handcrafted head
  k_pack_w<<<64, 256, 0, stream>>>(W1r, W1o, b1, wp1, b1f, flags, DIN);
  k_pack_w<<<128, 256, 0, stream>>>(W2r, W2o, b2, wp2, b2f, flags, DH);
  k_convert<<<2048, 256, 0, stream>>>(x, xb, flags, NN * DIN);
  k_colsum<<<512, 128, 0, stream>>>(x, colsum, flags);
  k_handcrafted<<<1, 128, 0, stream>>>(colsum, out, flags);

  // CSR build (once; reused by all 3 layers)
  k_deg<<<1024, 256, 0, stream>>>(ei, cnt, flags);
  k_scan1<<<nblk, SCAN_B, 0, stream>>>(cnt, rowptr, bsum);
  k_scan2<<<1, SCAN_B, 0, stream>>>(bsum, nblk);
  k_scan3<<<256, 256, 0, stream>>>(rowptr, bsum);
  k_fill<<<1024, 256, 0, stream>>>(ei, rowptr, cur, srcs, flags);

  // layer 1 (K = 128)
  k_gather<<<NN, DIN / 2, 0, stream>>>(rowptr, srcs, xb, aggb, DIN);
  k_gemm<<<gemm_grid, 256, 0, stream>>>(aggb, xb, wp1, b1f, h, DIN);
  // layer 2 (K = 256), h in-place (each block reads only rows it writes)
  k_gather<<<NN, DH / 2, 0, stream>>>(rowptr, srcs, h, aggb, DH);
  k_gemm<<<gemm_grid, 256, 0, stream>>>(aggb, h, wp2, b2f, h, DH);
  // layer 3 (K = 256, shared weights)
  k_gather<<<NN, DH / 2, 0, stream>>>(rowptr, srcs, h, aggb, DH);
  k_gemm<<<gemm_grid, 256, 0, stream>>>(aggb, h, wp2, b2f, h, DH);

  // mean pool: segment bounds (batch sorted by construction) + per-graph mean
  k_bounds<<<nblk, 256, 0, stream>>>(batch, gstart, gend, flags);
  k_poolseg<<<NG, DH, 0, stream>>>(gstart, gend, h, out, flags);
}

// Round 5
// 604.500 us; speedup vs baseline: 7.3675x; 1.3255x over previous
//
#include <hip/hip_runtime.h>
#include <hip/hip_bf16.h>
#include <string.h>

#define NN 50000
#define NE 800000
#define DIN 128
#define DH 256
#define NG 64
#define PSPLIT 8

typedef short bf16x8 __attribute__((ext_vector_type(8)));
typedef float f32x4 __attribute__((ext_vector_type(4)));

__device__ __forceinline__ float bf2f(__hip_bfloat16 v) { return __bfloat162float(v); }
__device__ __forceinline__ float bfbits(unsigned int lo16) {
  unsigned int u = lo16 << 16;
  float f;
  memcpy(&f, &u, 4);
  return f;
}
__device__ __forceinline__ unsigned int packbf2(float x, float y) {
  __hip_bfloat16 bx = __float2bfloat16(x), by = __float2bfloat16(y);
  unsigned short ux, uy;
  memcpy(&ux, &bx, 2);
  memcpy(&uy, &by, 2);
  return (unsigned int)ux | ((unsigned int)uy << 16);
}

// flag-driven generic accessors: fbf=1 -> floats stored as bf16; i64=1 -> ints stored as int64
__device__ __forceinline__ float loadF(const void* p, long i, int fbf) {
  return fbf ? bf2f(((const __hip_bfloat16*)p)[i]) : ((const float*)p)[i];
}
__device__ __forceinline__ void storeF(void* p, long i, float v, int fbf) {
  if (fbf) ((__hip_bfloat16*)p)[i] = __float2bfloat16(v);
  else ((float*)p)[i] = v;
}
__device__ __forceinline__ int loadI(const void* p, long i, int i64) {
  return i64 ? (int)((const long long*)p)[i] : ((const int*)p)[i];
}

__global__ void k_detect(const void* x, const void* ei, int* flags) {
  __shared__ int s_f32sig, s_i32sig;
  if (threadIdx.x == 0) { s_f32sig = 0; s_i32sig = 0; }
  __syncthreads();
  int t = threadIdx.x;
  const unsigned short* u = (const unsigned short*)x;
  int f = 0;
  for (int i = 2 * t; i < 8192; i += 512) if (u[i] >= 0x4000) f = 1;
  const unsigned int* w = (const unsigned int*)ei;
  int g = 0;
  for (int i = 2 * t + 1; i < 8192; i += 512) if (w[i] != 0u) g = 1;
  if (f) atomicOr(&s_f32sig, 1);
  if (g) atomicOr(&s_i32sig, 1);
  __syncthreads();
  if (t == 0) { flags[0] = s_f32sig ? 0 : 1; flags[1] = s_i32sig ? 0 : 1; }
}

__global__ void k_zero(int* __restrict__ p, int n) {
  int i = blockIdx.x * blockDim.x + threadIdx.x;
  int stride = gridDim.x * blockDim.x;
  for (; i < n; i += stride) p[i] = 0;
}

__global__ void k_colsum(const void* __restrict__ x, float* __restrict__ colsum,
                         const int* __restrict__ flags) {
  int fbf = flags[0];
  int col = threadIdx.x;  // 0..127
  float acc = 0.f;
  for (int r = blockIdx.x; r < NN; r += gridDim.x)
    acc += loadF(x, (long)r * DIN + col, fbf);
  atomicAdd(&colsum[col], acc);
}

__global__ void k_handcrafted(const float* __restrict__ colsum, void* __restrict__ out,
                              const int* __restrict__ flags) {
  __shared__ float s[DIN];
  int fbf = flags[0];
  int t = threadIdx.x;
  s[t] = colsum[t];
  __syncthreads();
  for (int off = DIN / 2; off > 0; off >>= 1) {
    if (t < off) s[t] += s[t + off];
    __syncthreads();
  }
  float g = s[0];
  storeF(out, NG * DH + t, colsum[t] / g, fbf);
  if (t == 0) storeF(out, NG * DH + DIN, logf(g), fbf);
}

// convert x (whatever float dtype) -> bf16 copy
__global__ void k_convert(const void* __restrict__ x, __hip_bfloat16* __restrict__ xb,
                          const int* __restrict__ flags, int n) {
  int fbf = flags[0];
  int i = blockIdx.x * blockDim.x + threadIdx.x;
  int stride = gridDim.x * blockDim.x;
  for (; i < n; i += stride) xb[i] = __float2bfloat16(loadF(x, i, fbf));
}

// pack weights into MFMA b-frag order:
// pack[m*K*DH + ((ct*KS + ks)*64 + l)*8 + j] = W_m[(ks*32 + (l>>4)*8 + j)*DH + ct*16 + (l&15)]
__global__ void k_pack_w(const void* __restrict__ Wrel, const void* __restrict__ Wroot,
                         const void* __restrict__ bias, __hip_bfloat16* __restrict__ pack,
                         float* __restrict__ biasf, const int* __restrict__ flags, int K) {
  int fbf = flags[0];
  int KS = K >> 5;
  int total = 2 * K * DH;
  int i = blockIdx.x * blockDim.x + threadIdx.x;
  int stride = gridDim.x * blockDim.x;
  for (int p = i; p < total; p += stride) {
    int m = p / (K * DH);
    int r = p % (K * DH);
    int j = r & 7;
    int l = (r >> 3) & 63;
    int q2 = r >> 9;       // ct*KS + ks
    int ks = q2 % KS;
    int ct = q2 / KS;
    int kk = ks * 32 + (l >> 4) * 8 + j;
    int col = ct * 16 + (l & 15);
    const void* W = m ? Wroot : Wrel;
    pack[p] = __float2bfloat16(loadF(W, (long)kk * DH + col, fbf));
  }
  if (i < DH) biasf[i] = loadF(bias, i, fbf);
}

// ---------- CSR build ----------
__global__ void k_deg(const void* __restrict__ ei, int* __restrict__ cnt,
                      const int* __restrict__ flags) {
  int i64 = flags[1];
  int e = blockIdx.x * blockDim.x + threadIdx.x;
  int stride = gridDim.x * blockDim.x;
  for (; e < NE; e += stride) {
    int d = loadI(ei, (long)NE + e, i64);
    d = min(max(d, 0), NN - 1);
    atomicAdd(&cnt[d], 1);
  }
}

#define SCAN_B 256
__global__ void k_scan1(const int* __restrict__ cnt, int* __restrict__ rowptr,
                        int* __restrict__ bsum) {
  __shared__ int s[SCAN_B];
  int b = blockIdx.x, t = threadIdx.x;
  int i = b * SCAN_B + t;
  int v = (i < NN) ? cnt[i] : 0;
  s[t] = v;
  __syncthreads();
  for (int off = 1; off < SCAN_B; off <<= 1) {
    int xv = (t >= off) ? s[t - off] : 0;
    __syncthreads();
    s[t] += xv;
    __syncthreads();
  }
  if (i < NN) rowptr[i] = s[t] - v;
  if (t == SCAN_B - 1) bsum[b] = s[t];
}

__global__ void k_scan2(int* __restrict__ bsum, int nb) {
  __shared__ int s[SCAN_B];
  int t = threadIdx.x;
  int v = (t < nb) ? bsum[t] : 0;
  s[t] = v;
  __syncthreads();
  for (int off = 1; off < SCAN_B; off <<= 1) {
    int xv = (t >= off) ? s[t - off] : 0;
    __syncthreads();
    s[t] += xv;
    __syncthreads();
  }
  if (t < nb) bsum[t] = s[t] - v;  // exclusive
}

__global__ void k_scan3(int* __restrict__ rowptr, const int* __restrict__ bsum) {
  int i = blockIdx.x * blockDim.x + threadIdx.x;
  int stride = gridDim.x * blockDim.x;
  for (; i < NN; i += stride) rowptr[i] += bsum[i >> 8];
  if (blockIdx.x == 0 && threadIdx.x == 0) rowptr[NN] = NE;
}

__global__ void k_fill(const void* __restrict__ ei, const int* __restrict__ rowptr,
                       int* __restrict__ cur, int* __restrict__ srcs,
                       const int* __restrict__ flags) {
  int i64 = flags[1];
  int e = blockIdx.x * blockDim.x + threadIdx.x;
  int stride = gridDim.x * blockDim.x;
  for (; e < NE; e += stride) {
    int s = loadI(ei, e, i64);
    int d = loadI(ei, (long)NE + e, i64);
    s = min(max(s, 0), NN - 1);
    d = min(max(d, 0), NN - 1);
    int p = atomicAdd(&cur[d], 1);
    srcs[rowptr[d] + p] = s;
  }
}

// ---------- gathers: one wave per node, whole row per wave-instruction ----------
// D=256: lane loads uint2 (8B = 4 bf16); 64 lanes * 8B = 512B row
__global__ __launch_bounds__(256) void k_gather256(
    const int* __restrict__ rowptr, const int* __restrict__ srcs,
    const __hip_bfloat16* __restrict__ h, __hip_bfloat16* __restrict__ agg) {
  int node = blockIdx.x * 4 + (threadIdx.x >> 6);
  if (node >= NN) return;
  int lane = threadIdx.x & 63;
  int beg = rowptr[node], end = rowptr[node + 1];
  const uint2* h2 = (const uint2*)h;  // 64 uint2 per row
  float a0 = 0.f, a1 = 0.f, a2 = 0.f, a3 = 0.f;
  int i = beg;
  for (; i + 1 < end; i += 2) {
    int s0 = srcs[i], s1 = srcs[i + 1];
    uint2 v0 = h2[(long)s0 * 64 + lane];
    uint2 v1 = h2[(long)s1 * 64 + lane];
    a0 += bfbits(v0.x & 0xffffu) + bfbits(v1.x & 0xffffu);
    a1 += bfbits(v0.x >> 16) + bfbits(v1.x >> 16);
    a2 += bfbits(v0.y & 0xffffu) + bfbits(v1.y & 0xffffu);
    a3 += bfbits(v0.y >> 16) + bfbits(v1.y >> 16);
  }
  if (i < end) {
    uint2 v0 = h2[(long)srcs[i] * 64 + lane];
    a0 += bfbits(v0.x & 0xffffu);
    a1 += bfbits(v0.x >> 16);
    a2 += bfbits(v0.y & 0xffffu);
    a3 += bfbits(v0.y >> 16);
  }
  uint2 o;
  o.x = packbf2(a0, a1);
  o.y = packbf2(a2, a3);
  ((uint2*)agg)[(long)node * 64 + lane] = o;
}

// D=128: lane loads uint (4B = 2 bf16); 64 lanes * 4B = 256B row
__global__ __launch_bounds__(256) void k_gather128(
    const int* __restrict__ rowptr, const int* __restrict__ srcs,
    const __hip_bfloat16* __restrict__ h, __hip_bfloat16* __restrict__ agg) {
  int node = blockIdx.x * 4 + (threadIdx.x >> 6);
  if (node >= NN) return;
  int lane = threadIdx.x & 63;
  int beg = rowptr[node], end = rowptr[node + 1];
  const unsigned int* h2 = (const unsigned int*)h;  // 64 uints per row
  float a0 = 0.f, a1 = 0.f;
  int i = beg;
  for (; i + 1 < end; i += 2) {
    unsigned int v0 = h2[(long)srcs[i] * 64 + lane];
    unsigned int v1 = h2[(long)srcs[i + 1] * 64 + lane];
    a0 += bfbits(v0 & 0xffffu) + bfbits(v1 & 0xffffu);
    a1 += bfbits(v0 >> 16) + bfbits(v1 >> 16);
  }
  if (i < end) {
    unsigned int v0 = h2[(long)srcs[i] * 64 + lane];
    a0 += bfbits(v0 & 0xffffu);
    a1 += bfbits(v0 >> 16);
  }
  ((unsigned int*)agg)[(long)node * 64 + lane] = packbf2(a0, a1);
}

// out[n][:] = relu(A1[n][:] @ Wrel + A2[n][:] @ Wroot + bias)
// block: 64 rows x 256 cols, 4 waves; wave w covers cols [64w, 64w+64)
__global__ __launch_bounds__(256) void k_gemm(
    const __hip_bfloat16* __restrict__ A1, const __hip_bfloat16* __restrict__ A2,
    const __hip_bfloat16* __restrict__ Wpack, const float* __restrict__ bias,
    __hip_bfloat16* __restrict__ out, int K) {
  int KS = K >> 5;
  int lane = threadIdx.x & 63;
  int wave = threadIdx.x >> 6;
  int m15 = lane & 15;
  int q = lane >> 4;
  int row0 = blockIdx.x * 64;
  const short* A1s = (const short*)A1;
  const short* A2s = (const short*)A2;
  const short* Wp = (const short*)Wpack;
  int wrootOfs = K * DH;  // elems: second packed matrix
  f32x4 acc[4][4] = {};
  for (int ks = 0; ks < KS; ++ks) {
    int kofs = ks * 32 + q * 8;
    bf16x8 a1[4], a2[4], b1[4], b2[4];
#pragma unroll
    for (int mt = 0; mt < 4; ++mt) {
      int r = row0 + mt * 16 + m15;
      if (r > NN - 1) r = NN - 1;
      a1[mt] = *(const bf16x8*)(A1s + r * K + kofs);
      a2[mt] = *(const bf16x8*)(A2s + r * K + kofs);
    }
#pragma unroll
    for (int ct = 0; ct < 4; ++ct) {
      int gct = wave * 4 + ct;
      const short* base = Wp + ((gct * KS + ks) * 64 + lane) * 8;
      b1[ct] = *(const bf16x8*)(base);
      b2[ct] = *(const bf16x8*)(base + wrootOfs);
    }
#pragma unroll
    for (int mt = 0; mt < 4; ++mt)
#pragma unroll
      for (int ct = 0; ct < 4; ++ct) {
        acc[mt][ct] = __builtin_amdgcn_mfma_f32_16x16x32_bf16(a1[mt], b1[ct], acc[mt][ct], 0, 0, 0);
        acc[mt][ct] = __builtin_amdgcn_mfma_f32_16x16x32_bf16(a2[mt], b2[ct], acc[mt][ct], 0, 0, 0);
      }
  }
#pragma unroll
  for (int mt = 0; mt < 4; ++mt)
#pragma unroll
    for (int ct = 0; ct < 4; ++ct) {
      int col = wave * 64 + ct * 16 + m15;
      float bv = bias[col];
#pragma unroll
      for (int r = 0; r < 4; ++r) {
        int row = row0 + mt * 16 + q * 4 + r;
        if (row < NN) {
          float v = acc[mt][ct][r] + bv;
          out[row * DH + col] = __float2bfloat16(fmaxf(v, 0.f));
        }
      }
    }
}

// ---------- pooling (batch is sorted -> segment bounds, no big atomics) ----------
__global__ void k_bounds(const void* __restrict__ batch, int* __restrict__ gstart,
                         int* __restrict__ gend, const int* __restrict__ flags) {
  int i64 = flags[1];
  int n = blockIdx.x * blockDim.x + threadIdx.x;
  if (n >= NN) return;
  int b = min(max(loadI(batch, n, i64), 0), NG - 1);
  int bp = (n == 0) ? -1 : min(max(loadI(batch, n - 1, i64), 0), NG - 1);
  if (b != bp) gstart[b] = n;
  int bn = (n == NN - 1) ? -1 : min(max(loadI(batch, n + 1, i64), 0), NG - 1);
  if (b != bn) gend[b] = n + 1;
}

// grid (NG, PSPLIT), block 128: each block partial-sums a slice of the graph's rows
__global__ void k_poolpart(const int* __restrict__ gstart, const int* __restrict__ gend,
                           const __hip_bfloat16* __restrict__ h, float* __restrict__ pooled) {
  int g = blockIdx.x;
  int p = blockIdx.y;
  int j = threadIdx.x;  // 0..127, 2 cols each
  int s = gstart[g], e = gend[g];
  int len = e - s;
  if (len <= 0) return;
  int chunk = (len + PSPLIT - 1) / PSPLIT;
  int rs = s + p * chunk;
  int re = min(rs + chunk, e);
  if (rs >= re) return;
  const unsigned int* h2 = (const unsigned int*)h;  // 128 uints per row
  float a0 = 0.f, a1 = 0.f;
  for (int r = rs; r < re; ++r) {
    unsigned int v = h2[(long)r * 128 + j];
    a0 += bfbits(v & 0xffffu);
    a1 += bfbits(v >> 16);
  }
  atomicAdd(&pooled[g * DH + 2 * j], a0);
  atomicAdd(&pooled[g * DH + 2 * j + 1], a1);
}

__global__ void k_poolfin(const int* __restrict__ gstart, const int* __restrict__ gend,
                          const float* __restrict__ pooled, void* __restrict__ out,
                          const int* __restrict__ flags) {
  int fbf = flags[0];
  int g = blockIdx.x;
  int j = threadIdx.x;
  float cnt = fmaxf((float)(gend[g] - gstart[g]), 1.0f);
  storeF(out, (long)g * DH + j, pooled[g * DH + j] / cnt, fbf);
}

extern "C" void kernel_launch(void* const* d_in, const int* in_sizes, int n_in,
                              void* d_out, int out_size, void* d_ws, size_t ws_size,
                              hipStream_t stream) {
  const void* x = d_in[0];
  const void* ei = d_in[1];
  const void* batch = d_in[2];
  const void* W1r = d_in[3];
  const void* W1o = d_in[4];
  const void* b1 = d_in[5];
  const void* W2r = d_in[6];
  const void* W2o = d_in[7];
  const void* b2 = d_in[8];
  void* out = d_out;

  // ---- workspace layout (256B-aligned chunks) ----
  char* w = (char*)d_ws;
  auto alloc = [&](size_t bytes) -> char* {
    char* p = w;
    w += (bytes + 255) & ~(size_t)255;
    return p;
  };
  int* flags = (int*)alloc(64);
  // contiguous zero region: cnt, cur, colsum, gstart, gend, pooled
  const int zero_n = NN + NN + DIN + NG + NG + NG * DH;
  int* zreg = (int*)alloc((size_t)zero_n * 4);
  int* cnt = zreg;
  int* cur = cnt + NN;
  float* colsum = (float*)(cur + NN);
  int* gstart = (int*)(colsum + DIN);
  int* gend = gstart + NG;
  float* pooled = (float*)(gend + NG);
  int* rowptr = (int*)alloc((NN + 1) * 4);
  int* bsum = (int*)alloc(SCAN_B * 4);
  int* srcs = (int*)alloc((size_t)NE * 4);
  __hip_bfloat16* xb = (__hip_bfloat16*)alloc((size_t)NN * DIN * 2);
  __hip_bfloat16* aggb = (__hip_bfloat16*)alloc((size_t)NN * DH * 2);
  __hip_bfloat16* h = (__hip_bfloat16*)alloc((size_t)NN * DH * 2);
  __hip_bfloat16* wp1 = (__hip_bfloat16*)alloc((size_t)2 * DIN * DH * 2);
  __hip_bfloat16* wp2 = (__hip_bfloat16*)alloc((size_t)2 * DH * DH * 2);
  float* b1f = (float*)alloc(DH * 4);
  float* b2f = (float*)alloc(DH * 4);

  const int nblk = (NN + SCAN_B - 1) / SCAN_B;  // 196
  const int gemm_grid = (NN + 63) / 64;          // 782
  const int gat_grid = (NN + 3) / 4;             // 12500

  k_detect<<<1, 256, 0, stream>>>(x, ei, flags);
  k_zero<<<512, 256, 0, stream>>>(zreg, zero_n);

  // weight packing + x conversion + handcrafted head
  k_pack_w<<<64, 256, 0, stream>>>(W1r, W1o, b1, wp1, b1f, flags, DIN);
  k_pack_w<<<128, 256, 0, stream>>>(W2r, W2o, b2, wp2, b2f, flags, DH);
  k_convert<<<2048, 256, 0, stream>>>(x, xb, flags, NN * DIN);
  k_colsum<<<512, 128, 0, stream>>>(x, colsum, flags);
  k_handcrafted<<<1, 128, 0, stream>>>(colsum, out, flags);

  // CSR build (once; reused by all 3 layers)
  k_deg<<<1024, 256, 0, stream>>>(ei, cnt, flags);
  k_scan1<<<nblk, SCAN_B, 0, stream>>>(cnt, rowptr, bsum);
  k_scan2<<<1, SCAN_B, 0, stream>>>(bsum, nblk);
  k_scan3<<<256, 256, 0, stream>>>(rowptr, bsum);
  k_fill<<<1024, 256, 0, stream>>>(ei, rowptr, cur, srcs, flags);

  // layer 1 (K = 128)
  k_gather128<<<gat_grid, 256, 0, stream>>>(rowptr, srcs, xb, aggb);
  k_gemm<<<gemm_grid, 256, 0, stream>>>(aggb, xb, wp1, b1f, h, DIN);
  // layer 2 (K = 256), h in-place (each block reads only rows it writes)
  k_gather256<<<gat_grid, 256, 0, stream>>>(rowptr, srcs, h, aggb);
  k_gemm<<<gemm_grid, 256, 0, stream>>>(aggb, h, wp2, b2f, h, DH);
  // layer 3 (K = 256, shared weights)
  k_gather256<<<gat_grid, 256, 0, stream>>>(rowptr, srcs, h, aggb);
  k_gemm<<<gemm_grid, 256, 0, stream>>>(aggb, h, wp2, b2f, h, DH);

  // mean pool: segment bounds (batch sorted) + split partial sums + finalize
  k_bounds<<<nblk, 256, 0, stream>>>(batch, gstart, gend, flags);
  k_poolpart<<<dim3(NG, PSPLIT), 128, 0, stream>>>(gstart, gend, h, pooled);
  k_poolfin<<<NG, DH, 0, stream>>>(gstart, gend, pooled, out, flags);
}

// Round 6
// 535.595 us; speedup vs baseline: 8.3154x; 1.1287x over previous
//
#include <hip/hip_runtime.h>
#include <hip/hip_bf16.h>
#include <string.h>

#define NN 50000
#define NE 800000
#define DIN 128
#define DH 256
#define NG 64
#define PSPLIT 32

typedef short bf16x8 __attribute__((ext_vector_type(8)));
typedef float f32x4 __attribute__((ext_vector_type(4)));

__device__ __forceinline__ float bf2f(__hip_bfloat16 v) { return __bfloat162float(v); }
__device__ __forceinline__ float bfbits(unsigned int lo16) {
  unsigned int u = lo16 << 16;
  float f;
  memcpy(&f, &u, 4);
  return f;
}
__device__ __forceinline__ unsigned int packbf2(float x, float y) {
  __hip_bfloat16 bx = __float2bfloat16(x), by = __float2bfloat16(y);
  unsigned short ux, uy;
  memcpy(&ux, &bx, 2);
  memcpy(&uy, &by, 2);
  return (unsigned int)ux | ((unsigned int)uy << 16);
}

// flag-driven generic accessors: fbf=1 -> floats stored as bf16; i64=1 -> ints stored as int64
__device__ __forceinline__ float loadF(const void* p, long i, int fbf) {
  return fbf ? bf2f(((const __hip_bfloat16*)p)[i]) : ((const float*)p)[i];
}
__device__ __forceinline__ void storeF(void* p, long i, float v, int fbf) {
  if (fbf) ((__hip_bfloat16*)p)[i] = __float2bfloat16(v);
  else ((float*)p)[i] = v;
}
__device__ __forceinline__ int loadI(const void* p, long i, int i64) {
  return i64 ? (int)((const long long*)p)[i] : ((const int*)p)[i];
}

__global__ void k_detect(const void* x, const void* ei, int* flags) {
  __shared__ int s_f32sig, s_i32sig;
  if (threadIdx.x == 0) { s_f32sig = 0; s_i32sig = 0; }
  __syncthreads();
  int t = threadIdx.x;
  const unsigned short* u = (const unsigned short*)x;
  int f = 0;
  for (int i = 2 * t; i < 8192; i += 512) if (u[i] >= 0x4000) f = 1;
  const unsigned int* w = (const unsigned int*)ei;
  int g = 0;
  for (int i = 2 * t + 1; i < 8192; i += 512) if (w[i] != 0u) g = 1;
  if (f) atomicOr(&s_f32sig, 1);
  if (g) atomicOr(&s_i32sig, 1);
  __syncthreads();
  if (t == 0) { flags[0] = s_f32sig ? 0 : 1; flags[1] = s_i32sig ? 0 : 1; }
}

__global__ void k_zero(int* __restrict__ p, int n) {
  int i = blockIdx.x * blockDim.x + threadIdx.x;
  int stride = gridDim.x * blockDim.x;
  for (; i < n; i += stride) p[i] = 0;
}

// fused: colsum partials + bf16 conversion of x (single pass over x)
__global__ void k_prep(const void* __restrict__ x, __hip_bfloat16* __restrict__ xb,
                       float* __restrict__ colsum, const int* __restrict__ flags) {
  int fbf = flags[0];
  int col = threadIdx.x;  // 0..127
  float acc = 0.f;
  for (int r = blockIdx.x; r < NN; r += gridDim.x) {
    float v = loadF(x, (long)r * DIN + col, fbf);
    acc += v;
    xb[(long)r * DIN + col] = __float2bfloat16(v);
  }
  atomicAdd(&colsum[col], acc);
}

__global__ void k_handcrafted(const float* __restrict__ colsum, void* __restrict__ out,
                              const int* __restrict__ flags) {
  __shared__ float s[DIN];
  int fbf = flags[0];
  int t = threadIdx.x;
  s[t] = colsum[t];
  __syncthreads();
  for (int off = DIN / 2; off > 0; off >>= 1) {
    if (t < off) s[t] += s[t + off];
    __syncthreads();
  }
  float g = s[0];
  storeF(out, NG * DH + t, colsum[t] / g, fbf);
  if (t == 0) storeF(out, NG * DH + DIN, logf(g), fbf);
}

// pack weights into MFMA b-frag order:
// pack[m*K*DH + ((ct*KS + ks)*64 + l)*8 + j] = W_m[(ks*32 + (l>>4)*8 + j)*DH + ct*16 + (l&15)]
__global__ void k_pack_w(const void* __restrict__ Wrel, const void* __restrict__ Wroot,
                         const void* __restrict__ bias, __hip_bfloat16* __restrict__ pack,
                         float* __restrict__ biasf, const int* __restrict__ flags, int K) {
  int fbf = flags[0];
  int KS = K >> 5;
  int total = 2 * K * DH;
  int i = blockIdx.x * blockDim.x + threadIdx.x;
  int stride = gridDim.x * blockDim.x;
  for (int p = i; p < total; p += stride) {
    int m = p / (K * DH);
    int r = p % (K * DH);
    int j = r & 7;
    int l = (r >> 3) & 63;
    int q2 = r >> 9;       // ct*KS + ks
    int ks = q2 % KS;
    int ct = q2 / KS;
    int kk = ks * 32 + (l >> 4) * 8 + j;
    int col = ct * 16 + (l & 15);
    const void* W = m ? Wroot : Wrel;
    pack[p] = __float2bfloat16(loadF(W, (long)kk * DH + col, fbf));
  }
  if (i < DH) biasf[i] = loadF(bias, i, fbf);
}

// ---------- CSR build ----------
__global__ void k_deg(const void* __restrict__ ei, int* __restrict__ cnt,
                      const int* __restrict__ flags) {
  int i64 = flags[1];
  int e = blockIdx.x * blockDim.x + threadIdx.x;
  int stride = gridDim.x * blockDim.x;
  for (; e < NE; e += stride) {
    int d = loadI(ei, (long)NE + e, i64);
    d = min(max(d, 0), NN - 1);
    atomicAdd(&cnt[d], 1);
  }
}

#define SCAN_B 256
__global__ void k_scan1(const int* __restrict__ cnt, int* __restrict__ rowptr,
                        int* __restrict__ bsum) {
  __shared__ int s[SCAN_B];
  int b = blockIdx.x, t = threadIdx.x;
  int i = b * SCAN_B + t;
  int v = (i < NN) ? cnt[i] : 0;
  s[t] = v;
  __syncthreads();
  for (int off = 1; off < SCAN_B; off <<= 1) {
    int xv = (t >= off) ? s[t - off] : 0;
    __syncthreads();
    s[t] += xv;
    __syncthreads();
  }
  if (i < NN) rowptr[i] = s[t] - v;
  if (t == SCAN_B - 1) bsum[b] = s[t];
}

__global__ void k_scan2(int* __restrict__ bsum, int nb) {
  __shared__ int s[SCAN_B];
  int t = threadIdx.x;
  int v = (t < nb) ? bsum[t] : 0;
  s[t] = v;
  __syncthreads();
  for (int off = 1; off < SCAN_B; off <<= 1) {
    int xv = (t >= off) ? s[t - off] : 0;
    __syncthreads();
    s[t] += xv;
    __syncthreads();
  }
  if (t < nb) bsum[t] = s[t] - v;  // exclusive
}

__global__ void k_scan3(int* __restrict__ rowptr, const int* __restrict__ bsum) {
  int i = blockIdx.x * blockDim.x + threadIdx.x;
  int stride = gridDim.x * blockDim.x;
  for (; i < NN; i += stride) rowptr[i] += bsum[i >> 8];
  if (blockIdx.x == 0 && threadIdx.x == 0) rowptr[NN] = NE;
}

__global__ void k_fill(const void* __restrict__ ei, const int* __restrict__ rowptr,
                       int* __restrict__ cur, int* __restrict__ srcs,
                       const int* __restrict__ flags) {
  int i64 = flags[1];
  int e = blockIdx.x * blockDim.x + threadIdx.x;
  int stride = gridDim.x * blockDim.x;
  for (; e < NE; e += stride) {
    int s = loadI(ei, e, i64);
    int d = loadI(ei, (long)NE + e, i64);
    s = min(max(s, 0), NN - 1);
    d = min(max(d, 0), NN - 1);
    int p = atomicAdd(&cur[d], 1);
    srcs[rowptr[d] + p] = s;
  }
}

// ---------- gathers: one wave per node, whole row per wave-instruction ----------
// D=256: lane loads uint2 (8B = 4 bf16); 64 lanes * 8B = 512B row; 4 rows in flight
__global__ __launch_bounds__(256) void k_gather256(
    const int* __restrict__ rowptr, const int* __restrict__ srcs,
    const __hip_bfloat16* __restrict__ h, __hip_bfloat16* __restrict__ agg) {
  int node = blockIdx.x * 4 + (threadIdx.x >> 6);
  if (node >= NN) return;
  int lane = threadIdx.x & 63;
  int beg = rowptr[node], end = rowptr[node + 1];
  const uint2* h2 = (const uint2*)h;  // 64 uint2 per row
  float a0 = 0.f, a1 = 0.f, a2 = 0.f, a3 = 0.f;
  int i = beg;
  for (; i + 3 < end; i += 4) {
    int s0 = srcs[i] * 64 + lane;
    int s1 = srcs[i + 1] * 64 + lane;
    int s2 = srcs[i + 2] * 64 + lane;
    int s3 = srcs[i + 3] * 64 + lane;
    uint2 v0 = h2[s0];
    uint2 v1 = h2[s1];
    uint2 v2 = h2[s2];
    uint2 v3 = h2[s3];
    a0 += bfbits(v0.x & 0xffffu) + bfbits(v1.x & 0xffffu) + bfbits(v2.x & 0xffffu) + bfbits(v3.x & 0xffffu);
    a1 += bfbits(v0.x >> 16) + bfbits(v1.x >> 16) + bfbits(v2.x >> 16) + bfbits(v3.x >> 16);
    a2 += bfbits(v0.y & 0xffffu) + bfbits(v1.y & 0xffffu) + bfbits(v2.y & 0xffffu) + bfbits(v3.y & 0xffffu);
    a3 += bfbits(v0.y >> 16) + bfbits(v1.y >> 16) + bfbits(v2.y >> 16) + bfbits(v3.y >> 16);
  }
  for (; i < end; ++i) {
    uint2 v0 = h2[srcs[i] * 64 + lane];
    a0 += bfbits(v0.x & 0xffffu);
    a1 += bfbits(v0.x >> 16);
    a2 += bfbits(v0.y & 0xffffu);
    a3 += bfbits(v0.y >> 16);
  }
  uint2 o;
  o.x = packbf2(a0, a1);
  o.y = packbf2(a2, a3);
  ((uint2*)agg)[node * 64 + lane] = o;
}

// D=128: lane loads uint (4B = 2 bf16); 64 lanes * 4B = 256B row; 4 rows in flight
__global__ __launch_bounds__(256) void k_gather128(
    const int* __restrict__ rowptr, const int* __restrict__ srcs,
    const __hip_bfloat16* __restrict__ h, __hip_bfloat16* __restrict__ agg) {
  int node = blockIdx.x * 4 + (threadIdx.x >> 6);
  if (node >= NN) return;
  int lane = threadIdx.x & 63;
  int beg = rowptr[node], end = rowptr[node + 1];
  const unsigned int* h2 = (const unsigned int*)h;  // 64 uints per row
  float a0 = 0.f, a1 = 0.f;
  int i = beg;
  for (; i + 3 < end; i += 4) {
    unsigned int v0 = h2[srcs[i] * 64 + lane];
    unsigned int v1 = h2[srcs[i + 1] * 64 + lane];
    unsigned int v2 = h2[srcs[i + 2] * 64 + lane];
    unsigned int v3 = h2[srcs[i + 3] * 64 + lane];
    a0 += bfbits(v0 & 0xffffu) + bfbits(v1 & 0xffffu) + bfbits(v2 & 0xffffu) + bfbits(v3 & 0xffffu);
    a1 += bfbits(v0 >> 16) + bfbits(v1 >> 16) + bfbits(v2 >> 16) + bfbits(v3 >> 16);
  }
  for (; i < end; ++i) {
    unsigned int v0 = h2[srcs[i] * 64 + lane];
    a0 += bfbits(v0 & 0xffffu);
    a1 += bfbits(v0 >> 16);
  }
  ((unsigned int*)agg)[node * 64 + lane] = packbf2(a0, a1);
}

// out[n][:] = relu(A1[n][:] @ Wrel + A2[n][:] @ Wroot + bias)
// block: 64 rows x 256 cols, 4 waves; wave w covers cols [64w, 64w+64)
__global__ __launch_bounds__(256) void k_gemm(
    const __hip_bfloat16* __restrict__ A1, const __hip_bfloat16* __restrict__ A2,
    const __hip_bfloat16* __restrict__ Wpack, const float* __restrict__ bias,
    __hip_bfloat16* __restrict__ out, int K) {
  int KS = K >> 5;
  int lane = threadIdx.x & 63;
  int wave = threadIdx.x >> 6;
  int m15 = lane & 15;
  int q = lane >> 4;
  int row0 = blockIdx.x * 64;
  const short* A1s = (const short*)A1;
  const short* A2s = (const short*)A2;
  const short* Wp = (const short*)Wpack;
  int wrootOfs = K * DH;  // elems: second packed matrix
  f32x4 acc[4][4] = {};
  for (int ks = 0; ks < KS; ++ks) {
    int kofs = ks * 32 + q * 8;
    bf16x8 a1[4], a2[4], b1[4], b2[4];
#pragma unroll
    for (int mt = 0; mt < 4; ++mt) {
      int r = row0 + mt * 16 + m15;
      if (r > NN - 1) r = NN - 1;
      a1[mt] = *(const bf16x8*)(A1s + r * K + kofs);
      a2[mt] = *(const bf16x8*)(A2s + r * K + kofs);
    }
#pragma unroll
    for (int ct = 0; ct < 4; ++ct) {
      int gct = wave * 4 + ct;
      const short* base = Wp + ((gct * KS + ks) * 64 + lane) * 8;
      b1[ct] = *(const bf16x8*)(base);
      b2[ct] = *(const bf16x8*)(base + wrootOfs);
    }
#pragma unroll
    for (int mt = 0; mt < 4; ++mt)
#pragma unroll
      for (int ct = 0; ct < 4; ++ct) {
        acc[mt][ct] = __builtin_amdgcn_mfma_f32_16x16x32_bf16(a1[mt], b1[ct], acc[mt][ct], 0, 0, 0);
        acc[mt][ct] = __builtin_amdgcn_mfma_f32_16x16x32_bf16(a2[mt], b2[ct], acc[mt][ct], 0, 0, 0);
      }
  }
#pragma unroll
  for (int mt = 0; mt < 4; ++mt)
#pragma unroll
    for (int ct = 0; ct < 4; ++ct) {
      int col = wave * 64 + ct * 16 + m15;
      float bv = bias[col];
#pragma unroll
      for (int r = 0; r < 4; ++r) {
        int row = row0 + mt * 16 + q * 4 + r;
        if (row < NN) {
          float v = acc[mt][ct][r] + bv;
          out[row * DH + col] = __float2bfloat16(fmaxf(v, 0.f));
        }
      }
    }
}

// ---------- pooling (batch is sorted -> segment bounds, no big atomics) ----------
__global__ void k_bounds(const void* __restrict__ batch, int* __restrict__ gstart,
                         int* __restrict__ gend, const int* __restrict__ flags) {
  int i64 = flags[1];
  int n = blockIdx.x * blockDim.x + threadIdx.x;
  if (n >= NN) return;
  int b = min(max(loadI(batch, n, i64), 0), NG - 1);
  int bp = (n == 0) ? -1 : min(max(loadI(batch, n - 1, i64), 0), NG - 1);
  if (b != bp) gstart[b] = n;
  int bn = (n == NN - 1) ? -1 : min(max(loadI(batch, n + 1, i64), 0), NG - 1);
  if (b != bn) gend[b] = n + 1;
}

// grid (NG, PSPLIT), block 128: each block partial-sums a slice of the graph's rows
__global__ void k_poolpart(const int* __restrict__ gstart, const int* __restrict__ gend,
                           const __hip_bfloat16* __restrict__ h, float* __restrict__ pooled) {
  int g = blockIdx.x;
  int p = blockIdx.y;
  int j = threadIdx.x;  // 0..127, 2 cols each
  int s = gstart[g], e = gend[g];
  int len = e - s;
  if (len <= 0) return;
  int chunk = (len + PSPLIT - 1) / PSPLIT;
  int rs = s + p * chunk;
  int re = min(rs + chunk, e);
  if (rs >= re) return;
  const unsigned int* h2 = (const unsigned int*)h;  // 128 uints per row
  float a0 = 0.f, a1 = 0.f;
  for (int r = rs; r < re; ++r) {
    unsigned int v = h2[(long)r * 128 + j];
    a0 += bfbits(v & 0xffffu);
    a1 += bfbits(v >> 16);
  }
  atomicAdd(&pooled[g * DH + 2 * j], a0);
  atomicAdd(&pooled[g * DH + 2 * j + 1], a1);
}

__global__ void k_poolfin(const int* __restrict__ gstart, const int* __restrict__ gend,
                          const float* __restrict__ pooled, void* __restrict__ out,
                          const int* __restrict__ flags) {
  int fbf = flags[0];
  int g = blockIdx.x;
  int j = threadIdx.x;
  float cnt = fmaxf((float)(gend[g] - gstart[g]), 1.0f);
  storeF(out, (long)g * DH + j, pooled[g * DH + j] / cnt, fbf);
}

extern "C" void kernel_launch(void* const* d_in, const int* in_sizes, int n_in,
                              void* d_out, int out_size, void* d_ws, size_t ws_size,
                              hipStream_t stream) {
  const void* x = d_in[0];
  const void* ei = d_in[1];
  const void* batch = d_in[2];
  const void* W1r = d_in[3];
  const void* W1o = d_in[4];
  const void* b1 = d_in[5];
  const void* W2r = d_in[6];
  const void* W2o = d_in[7];
  const void* b2 = d_in[8];
  void* out = d_out;

  // ---- workspace layout (256B-aligned chunks) ----
  char* w = (char*)d_ws;
  auto alloc = [&](size_t bytes) -> char* {
    char* p = w;
    w += (bytes + 255) & ~(size_t)255;
    return p;
  };
  int* flags = (int*)alloc(64);
  // contiguous zero region: cnt, cur, colsum, gstart, gend, pooled
  const int zero_n = NN + NN + DIN + NG + NG + NG * DH;
  int* zreg = (int*)alloc((size_t)zero_n * 4);
  int* cnt = zreg;
  int* cur = cnt + NN;
  float* colsum = (float*)(cur + NN);
  int* gstart = (int*)(colsum + DIN);
  int* gend = gstart + NG;
  float* pooled = (float*)(gend + NG);
  int* rowptr = (int*)alloc((NN + 1) * 4);
  int* bsum = (int*)alloc(SCAN_B * 4);
  int* srcs = (int*)alloc((size_t)NE * 4);
  __hip_bfloat16* xb = (__hip_bfloat16*)alloc((size_t)NN * DIN * 2);
  __hip_bfloat16* aggb = (__hip_bfloat16*)alloc((size_t)NN * DH * 2);
  __hip_bfloat16* h = (__hip_bfloat16*)alloc((size_t)NN * DH * 2);
  __hip_bfloat16* wp1 = (__hip_bfloat16*)alloc((size_t)2 * DIN * DH * 2);
  __hip_bfloat16* wp2 = (__hip_bfloat16*)alloc((size_t)2 * DH * DH * 2);
  float* b1f = (float*)alloc(DH * 4);
  float* b2f = (float*)alloc(DH * 4);

  const int nblk = (NN + SCAN_B - 1) / SCAN_B;  // 196
  const int gemm_grid = (NN + 63) / 64;          // 782
  const int gat_grid = (NN + 3) / 4;             // 12500

  k_detect<<<1, 256, 0, stream>>>(x, ei, flags);
  k_zero<<<512, 256, 0, stream>>>(zreg, zero_n);

  // weight packing + fused colsum/convert + handcrafted head
  k_pack_w<<<64, 256, 0, stream>>>(W1r, W1o, b1, wp1, b1f, flags, DIN);
  k_pack_w<<<128, 256, 0, stream>>>(W2r, W2o, b2, wp2, b2f, flags, DH);
  k_prep<<<512, 128, 0, stream>>>(x, xb, colsum, flags);
  k_handcrafted<<<1, 128, 0, stream>>>(colsum, out, flags);

  // CSR build (once; reused by all 3 layers)
  k_deg<<<1024, 256, 0, stream>>>(ei, cnt, flags);
  k_scan1<<<nblk, SCAN_B, 0, stream>>>(cnt, rowptr, bsum);
  k_scan2<<<1, SCAN_B, 0, stream>>>(bsum, nblk);
  k_scan3<<<256, 256, 0, stream>>>(rowptr, bsum);
  k_fill<<<1024, 256, 0, stream>>>(ei, rowptr, cur, srcs, flags);

  // layer 1 (K = 128)
  k_gather128<<<gat_grid, 256, 0, stream>>>(rowptr, srcs, xb, aggb);
  k_gemm<<<gemm_grid, 256, 0, stream>>>(aggb, xb, wp1, b1f, h, DIN);
  // layer 2 (K = 256), h in-place (each block reads only rows it writes)
  k_gather256<<<gat_grid, 256, 0, stream>>>(rowptr, srcs, h, aggb);
  k_gemm<<<gemm_grid, 256, 0, stream>>>(aggb, h, wp2, b2f, h, DH);
  // layer 3 (K = 256, shared weights)
  k_gather256<<<gat_grid, 256, 0, stream>>>(rowptr, srcs, h, aggb);
  k_gemm<<<gemm_grid, 256, 0, stream>>>(aggb, h, wp2, b2f, h, DH);

  // mean pool: segment bounds (batch sorted) + split partial sums + finalize
  k_bounds<<<nblk, 256, 0, stream>>>(batch, gstart, gend, flags);
  k_poolpart<<<dim3(NG, PSPLIT), 128, 0, stream>>>(gstart, gend, h, pooled);
  k_poolfin<<<NG, DH, 0, stream>>>(gstart, gend, pooled, out, flags);
}